// Round 1
// baseline (343.662 us; speedup 1.0000x reference)
//
#include <hip/hip_runtime.h>
#include <math.h>

#define NTOK 512      // N
#define BATCH 2
#define HID 256
#define HEADS 4
#define HD 64
#define NEG_INF -1e9f

// ---------------------------------------------------------------------------
// Stage A: fused 5-way projection GEMM.  Y = X @ W (+bias)
//   grid.x = 64 (row tiles of 16 over M=B*N=1024), grid.y = 5 (which matrix)
//   y=0..2 -> Q,K,V ; y=3 -> A = x@Wp1[:256] + bp1 ; y=4 -> BbT = (x@Wp1[256:])^T
// ---------------------------------------------------------------------------
__global__ __launch_bounds__(256) void pga_proj5(
    const float* __restrict__ x,
    const float* __restrict__ Wq, const float* __restrict__ bq,
    const float* __restrict__ Wk, const float* __restrict__ bk,
    const float* __restrict__ Wv, const float* __restrict__ bv,
    const float* __restrict__ Wp1, const float* __restrict__ bp1,
    float* __restrict__ Q, float* __restrict__ K, float* __restrict__ V,
    float* __restrict__ A, float* __restrict__ BbT)
{
    __shared__ float xs[16][HID];
    const int m0 = blockIdx.x * 16;
    const int which = blockIdx.y;
    const int t = threadIdx.x;          // column c = t

    #pragma unroll
    for (int r = 0; r < 16; ++r) xs[r][t] = x[(m0 + r) * HID + t];
    __syncthreads();

    const float* W; const float* bvec; float* out; bool transposed = false;
    switch (which) {
        case 0: W = Wq; bvec = bq; out = Q; break;
        case 1: W = Wk; bvec = bk; out = K; break;
        case 2: W = Wv; bvec = bv; out = V; break;
        case 3: W = Wp1; bvec = bp1; out = A; break;
        default: W = Wp1 + HID * HID; bvec = nullptr; out = BbT; transposed = true; break;
    }

    float bcol = bvec ? bvec[t] : 0.0f;
    float acc[16];
    #pragma unroll
    for (int r = 0; r < 16; ++r) acc[r] = bcol;

    for (int kq = 0; kq < HID / 4; ++kq) {
        const float w0 = W[(kq * 4 + 0) * HID + t];
        const float w1 = W[(kq * 4 + 1) * HID + t];
        const float w2 = W[(kq * 4 + 2) * HID + t];
        const float w3 = W[(kq * 4 + 3) * HID + t];
        #pragma unroll
        for (int r = 0; r < 16; ++r) {
            float4 xv = ((const float4*)xs[r])[kq];
            acc[r] += xv.x * w0 + xv.y * w1 + xv.z * w2 + xv.w * w3;
        }
    }

    if (!transposed) {
        #pragma unroll
        for (int r = 0; r < 16; ++r) out[(m0 + r) * HID + t] = acc[r];
    } else {
        const int b = m0 >= NTOK;
        const int n0 = m0 - b * NTOK;
        #pragma unroll
        for (int r = 0; r < 16; ++r)
            out[b * (HID * NTOK) + t * NTOK + (n0 + r)] = acc[r];
    }
}

// ---------------------------------------------------------------------------
// Stage B: physics bias.  bias[b][h][i][j] = Wp2^T gelu(a_i + b_j) + bp2
//   grid = B * N/4 = 256 blocks, 512 threads; thread = j, block = 4 i-rows
// ---------------------------------------------------------------------------
__global__ __launch_bounds__(512) void pga_bias(
    const float* __restrict__ A, const float* __restrict__ BbT,
    const float* __restrict__ Wp2, const float* __restrict__ bp2,
    float* __restrict__ biasg)
{
    __shared__ float as[4][HID];
    __shared__ float4 wp[HID];

    const int t = threadIdx.x;          // j = t
    const int blk = blockIdx.x;
    const int b = blk >> 7;
    const int i0 = (blk & 127) * 4;

    if (t < HID) wp[t] = ((const float4*)Wp2)[t];      // Wp2[d][0..3]
    for (int idx = t; idx < 4 * HID; idx += 512) {
        int r = idx >> 8, d = idx & 255;
        as[r][d] = A[(b * NTOK + i0 + r) * HID + d];
    }
    __syncthreads();

    float acc[4][4];
    #pragma unroll
    for (int r = 0; r < 4; ++r)
        #pragma unroll
        for (int h = 0; h < 4; ++h) acc[r][h] = 0.0f;

    const float* bb = BbT + b * (HID * NTOK);          // [256][512]
    #pragma unroll 4
    for (int d = 0; d < HID; ++d) {
        const float bvv = bb[d * NTOK + t];            // coalesced across lanes
        const float4 w = wp[d];                        // broadcast
        #pragma unroll
        for (int r = 0; r < 4; ++r) {
            const float tt = as[r][d] + bvv;
            const float g = 0.5f * tt * (1.0f + erff(tt * 0.70710678118654752f));
            acc[r][0] += g * w.x; acc[r][1] += g * w.y;
            acc[r][2] += g * w.z; acc[r][3] += g * w.w;
        }
    }

    const float p0 = bp2[0], p1 = bp2[1], p2 = bp2[2], p3 = bp2[3];
    #pragma unroll
    for (int r = 0; r < 4; ++r) {
        const int i = i0 + r;
        float* o = biasg + ((size_t)(b * HEADS) * NTOK + i) * NTOK + t;
        o[0 * NTOK * NTOK] = acc[r][0] + p0;
        o[1 * NTOK * NTOK] = acc[r][1] + p1;
        o[2 * NTOK * NTOK] = acc[r][2] + p2;
        o[3 * NTOK * NTOK] = acc[r][3] + p3;
    }
}

// ---------------------------------------------------------------------------
// Stage C: attention.  grid = B*H*(N/4) = 1024 blocks, 256 threads (4 waves)
//   wave w handles row i = i0 + w.  K/V tiles of 128 rows staged in LDS.
// ---------------------------------------------------------------------------
__global__ __launch_bounds__(256) void pga_attn(
    const float* __restrict__ Q, const float* __restrict__ K,
    const float* __restrict__ V, const float* __restrict__ biasg,
    const int* __restrict__ adj, float* __restrict__ O)
{
    __shared__ float Ks[128][HD + 4];   // pad 4: float4-aligned, banks spread
    __shared__ float Ps[4][NTOK];
    __shared__ float qs[4][HD];

    const int blk = blockIdx.x;
    const int i0 = (blk & 127) * 4;
    const int h = (blk >> 7) & 3;
    const int b = blk >> 9;
    const int t = threadIdx.x;
    const int w = t >> 6;
    const int lane = t & 63;
    const int i = i0 + w;

    { int r = t >> 6, d = t & 63;
      qs[r][d] = Q[(b * NTOK + i0 + r) * HID + h * HD + d]; }

    const float scale = 0.125f;  // 1/sqrt(64)
    float S[8];

    // ---- phase 1: scores S[i][j] for all 512 j ----
    for (int jt = 0; jt < 4; ++jt) {
        __syncthreads();
        for (int idx = t; idx < 128 * HD; idx += 256) {
            int r = idx >> 6, d = idx & 63;
            Ks[r][d] = K[(b * NTOK + jt * 128 + r) * HID + h * HD + d];
        }
        __syncthreads();
        #pragma unroll
        for (int jr = 0; jr < 2; ++jr) {
            const int jl = jr * 64 + lane;
            const int j = jt * 128 + jl;
            const float4* kr = (const float4*)Ks[jl];
            const float4* qr = (const float4*)qs[w];
            float acc = 0.0f;
            #pragma unroll
            for (int dq = 0; dq < HD / 4; ++dq) {
                float4 kq = kr[dq]; float4 qq = qr[dq];
                acc += kq.x * qq.x + kq.y * qq.y + kq.z * qq.z + kq.w * qq.w;
            }
            const float bvv = biasg[(((size_t)(b * HEADS + h)) * NTOK + i) * NTOK + j];
            const int mv = adj[i * NTOK + j];
            S[jt * 2 + jr] = acc * scale + (mv > 0 ? bvv : NEG_INF);
        }
    }

    // ---- phase 2: softmax over the row (registers + shuffle butterfly) ----
    float mx = S[0];
    #pragma unroll
    for (int k = 1; k < 8; ++k) mx = fmaxf(mx, S[k]);
    for (int off = 32; off; off >>= 1) mx = fmaxf(mx, __shfl_xor(mx, off, 64));
    float l = 0.0f, p[8];
    #pragma unroll
    for (int k = 0; k < 8; ++k) { p[k] = __expf(S[k] - mx); l += p[k]; }
    for (int off = 32; off; off >>= 1) l += __shfl_xor(l, off, 64);
    const float inv = 1.0f / l;
    #pragma unroll
    for (int k = 0; k < 8; ++k) {
        const int j = (k >> 1) * 128 + (k & 1) * 64 + lane;
        Ps[w][j] = p[k] * inv;
    }

    // ---- phase 3: O = P @ V  (lane = d) ----
    float acc = 0.0f;
    for (int jt = 0; jt < 4; ++jt) {
        __syncthreads();
        for (int idx = t; idx < 128 * HD; idx += 256) {
            int r = idx >> 6, d = idx & 63;
            Ks[r][d] = V[(b * NTOK + jt * 128 + r) * HID + h * HD + d];
        }
        __syncthreads();
        #pragma unroll 4
        for (int jl = 0; jl < 128; ++jl)
            acc += Ps[w][jt * 128 + jl] * Ks[jl][lane];
    }
    O[(b * NTOK + i) * HID + h * HD + lane] = acc;
}

// ---------------------------------------------------------------------------
// Stage D: out = O @ Wo + bo
// ---------------------------------------------------------------------------
__global__ __launch_bounds__(256) void pga_outproj(
    const float* __restrict__ O, const float* __restrict__ Wo,
    const float* __restrict__ bo, float* __restrict__ out)
{
    __shared__ float xs[16][HID];
    const int m0 = blockIdx.x * 16;
    const int t = threadIdx.x;

    #pragma unroll
    for (int r = 0; r < 16; ++r) xs[r][t] = O[(m0 + r) * HID + t];
    __syncthreads();

    float acc[16];
    const float bcol = bo[t];
    #pragma unroll
    for (int r = 0; r < 16; ++r) acc[r] = bcol;

    for (int kq = 0; kq < HID / 4; ++kq) {
        const float w0 = Wo[(kq * 4 + 0) * HID + t];
        const float w1 = Wo[(kq * 4 + 1) * HID + t];
        const float w2 = Wo[(kq * 4 + 2) * HID + t];
        const float w3 = Wo[(kq * 4 + 3) * HID + t];
        #pragma unroll
        for (int r = 0; r < 16; ++r) {
            float4 xv = ((const float4*)xs[r])[kq];
            acc[r] += xv.x * w0 + xv.y * w1 + xv.z * w2 + xv.w * w3;
        }
    }
    #pragma unroll
    for (int r = 0; r < 16; ++r) out[(m0 + r) * HID + t] = acc[r];
}

extern "C" void kernel_launch(void* const* d_in, const int* in_sizes, int n_in,
                              void* d_out, int out_size, void* d_ws, size_t ws_size,
                              hipStream_t stream) {
    const float* x   = (const float*)d_in[0];
    const int*   adj = (const int*)d_in[1];
    const float* Wq  = (const float*)d_in[2];
    const float* bq  = (const float*)d_in[3];
    const float* Wk  = (const float*)d_in[4];
    const float* bk  = (const float*)d_in[5];
    const float* Wv  = (const float*)d_in[6];
    const float* bv  = (const float*)d_in[7];
    const float* Wo  = (const float*)d_in[8];
    const float* bo  = (const float*)d_in[9];
    const float* Wp1 = (const float*)d_in[10];
    const float* bp1 = (const float*)d_in[11];
    const float* Wp2 = (const float*)d_in[12];
    const float* bp2 = (const float*)d_in[13];
    float* out = (float*)d_out;

    // ws layout (floats): Q,K,V,A,BbT,O each 262144; bias 4194304
    float* ws   = (float*)d_ws;
    float* Q    = ws;
    float* K    = ws + 262144;
    float* V    = ws + 2 * 262144;
    float* A    = ws + 3 * 262144;
    float* BbT  = ws + 4 * 262144;
    float* O    = ws + 5 * 262144;
    float* bias = ws + 6 * 262144;

    pga_proj5<<<dim3(64, 5), 256, 0, stream>>>(x, Wq, bq, Wk, bk, Wv, bv,
                                               Wp1, bp1, Q, K, V, A, BbT);
    pga_bias<<<256, 512, 0, stream>>>(A, BbT, Wp2, bp2, bias);
    pga_attn<<<1024, 256, 0, stream>>>(Q, K, V, bias, adj, O);
    pga_outproj<<<64, 256, 0, stream>>>(O, Wo, bo, out);
}

// Round 2
// 272.516 us; speedup vs baseline: 1.2611x; 1.2611x over previous
//
#include <hip/hip_runtime.h>
#include <math.h>

#define NTOK 512      // N
#define BATCH 2
#define HID 256
#define HEADS 4
#define HD 64
#define NEG_INF -1e9f

// Branch-free gelu via Abramowitz-Stegun 7.1.26 erf (max erf err 1.5e-7).
// gelu(x) = x * Phi(x);  Phi(-|x|) = 0.5*poly(t)*exp(-x^2/2), t=1/(1+p*|x|/sqrt2)
__device__ __forceinline__ float fast_gelu(float x) {
    const float z = fabsf(x) * 0.70710678118654752f;
    const float t = __builtin_amdgcn_rcpf(fmaf(0.3275911f, z, 1.0f));
    float p = fmaf(1.061405429f, t, -1.453152027f);
    p = fmaf(p, t, 1.421413741f);
    p = fmaf(p, t, -0.284496736f);
    p = fmaf(p, t, 0.254829592f);
    p = p * t;
    const float E = __expf(-(z * z));
    const float phin = 0.5f * p * E;                 // Phi(-|x|)
    const float phi = (x >= 0.0f) ? 1.0f - phin : phin;
    return x * phi;
}

__device__ __forceinline__ float lane_bcast(float v, int l) {
    return __int_as_float(__builtin_amdgcn_readlane(__float_as_int(v), l));
}

// ---------------------------------------------------------------------------
// Stage A: fused 5-way projection GEMM.  Y = X @ W (+bias)
// ---------------------------------------------------------------------------
__global__ __launch_bounds__(256) void pga_proj5(
    const float* __restrict__ x,
    const float* __restrict__ Wq, const float* __restrict__ bq,
    const float* __restrict__ Wk, const float* __restrict__ bk,
    const float* __restrict__ Wv, const float* __restrict__ bv,
    const float* __restrict__ Wp1, const float* __restrict__ bp1,
    float* __restrict__ Q, float* __restrict__ K, float* __restrict__ V,
    float* __restrict__ A, float* __restrict__ BbT)
{
    __shared__ float xs[16][HID];
    const int m0 = blockIdx.x * 16;
    const int which = blockIdx.y;
    const int t = threadIdx.x;          // column c = t

    #pragma unroll
    for (int r = 0; r < 16; ++r) xs[r][t] = x[(m0 + r) * HID + t];
    __syncthreads();

    const float* W; const float* bvec; float* out; bool transposed = false;
    switch (which) {
        case 0: W = Wq; bvec = bq; out = Q; break;
        case 1: W = Wk; bvec = bk; out = K; break;
        case 2: W = Wv; bvec = bv; out = V; break;
        case 3: W = Wp1; bvec = bp1; out = A; break;
        default: W = Wp1 + HID * HID; bvec = nullptr; out = BbT; transposed = true; break;
    }

    float bcol = bvec ? bvec[t] : 0.0f;
    float acc[16];
    #pragma unroll
    for (int r = 0; r < 16; ++r) acc[r] = bcol;

    for (int kq = 0; kq < HID / 4; ++kq) {
        const float w0 = W[(kq * 4 + 0) * HID + t];
        const float w1 = W[(kq * 4 + 1) * HID + t];
        const float w2 = W[(kq * 4 + 2) * HID + t];
        const float w3 = W[(kq * 4 + 3) * HID + t];
        #pragma unroll
        for (int r = 0; r < 16; ++r) {
            float4 xv = ((const float4*)xs[r])[kq];
            acc[r] += xv.x * w0 + xv.y * w1 + xv.z * w2 + xv.w * w3;
        }
    }

    if (!transposed) {
        #pragma unroll
        for (int r = 0; r < 16; ++r) out[(m0 + r) * HID + t] = acc[r];
    } else {
        const int b = m0 >= NTOK;
        const int n0 = m0 - b * NTOK;
        #pragma unroll
        for (int r = 0; r < 16; ++r)
            out[b * (HID * NTOK) + t * NTOK + (n0 + r)] = acc[r];
    }
}

// ---------------------------------------------------------------------------
// Stage B: physics bias.  bias[b][h][i][j] = Wp2^T gelu(a_i + b_j) + bp2
//   grid = B * N/2 = 512 blocks, 512 threads; thread = j, block = 2 i-rows
// ---------------------------------------------------------------------------
__global__ __launch_bounds__(512) void pga_bias(
    const float* __restrict__ A, const float* __restrict__ BbT,
    const float* __restrict__ Wp2, const float* __restrict__ bp2,
    float* __restrict__ biasg)
{
    __shared__ float as[2][HID];
    __shared__ float4 wp[HID];

    const int t = threadIdx.x;          // j = t
    const int blk = blockIdx.x;
    const int b = blk >> 8;
    const int i0 = (blk & 255) * 2;

    if (t < HID) wp[t] = ((const float4*)Wp2)[t];      // Wp2[d][0..3]
    if (t < 2 * HID) {
        int r = t >> 8, d = t & 255;
        as[r][d] = A[(b * NTOK + i0 + r) * HID + d];
    }
    __syncthreads();

    float acc[2][4];
    #pragma unroll
    for (int r = 0; r < 2; ++r)
        #pragma unroll
        for (int h = 0; h < 4; ++h) acc[r][h] = 0.0f;

    const float* bb = BbT + b * (HID * NTOK);          // [256][512]
    #pragma unroll 4
    for (int d = 0; d < HID; ++d) {
        const float bvv = bb[d * NTOK + t];            // coalesced across lanes
        const float4 w = wp[d];                        // broadcast
        #pragma unroll
        for (int r = 0; r < 2; ++r) {
            const float g = fast_gelu(as[r][d] + bvv);
            acc[r][0] += g * w.x; acc[r][1] += g * w.y;
            acc[r][2] += g * w.z; acc[r][3] += g * w.w;
        }
    }

    const float p0 = bp2[0], p1 = bp2[1], p2 = bp2[2], p3 = bp2[3];
    #pragma unroll
    for (int r = 0; r < 2; ++r) {
        const int i = i0 + r;
        float* o = biasg + ((size_t)(b * HEADS) * NTOK + i) * NTOK + t;
        o[0 * NTOK * NTOK] = acc[r][0] + p0;
        o[1 * NTOK * NTOK] = acc[r][1] + p1;
        o[2 * NTOK * NTOK] = acc[r][2] + p2;
        o[3 * NTOK * NTOK] = acc[r][3] + p3;
    }
}

// ---------------------------------------------------------------------------
// Stage C: attention.  grid = B*H*(N/4) = 1024 blocks, 256 threads (4 waves)
//   wave w handles row i = i0 + w.  K/V tiles of 128 rows staged in LDS.
//   P stays in registers; broadcast via v_readlane in the PV phase.
// ---------------------------------------------------------------------------
__global__ __launch_bounds__(256) void pga_attn(
    const float* __restrict__ Q, const float* __restrict__ K,
    const float* __restrict__ V, const float* __restrict__ biasg,
    const int* __restrict__ adj, float* __restrict__ O)
{
    __shared__ float Ks[128][HD + 4];   // pad 4: float4-aligned, banks spread
    __shared__ float qs[4][HD];

    const int blk = blockIdx.x;
    const int i0 = (blk & 127) * 4;
    const int h = (blk >> 7) & 3;
    const int b = blk >> 9;
    const int t = threadIdx.x;
    const int w = t >> 6;
    const int lane = t & 63;
    const int i = i0 + w;

    { int r = t >> 6, d = t & 63;
      qs[r][d] = Q[(b * NTOK + i0 + r) * HID + h * HD + d]; }

    const float scale = 0.125f;  // 1/sqrt(64)
    float S[8];

    // ---- phase 1: scores S[i][j] for all 512 j ----
    for (int jt = 0; jt < 4; ++jt) {
        __syncthreads();
        for (int idx = t; idx < 128 * HD; idx += 256) {
            int r = idx >> 6, d = idx & 63;
            Ks[r][d] = K[(b * NTOK + jt * 128 + r) * HID + h * HD + d];
        }
        __syncthreads();
        #pragma unroll
        for (int jr = 0; jr < 2; ++jr) {
            const int jl = jr * 64 + lane;
            const int j = jt * 128 + jl;
            const float4* kr = (const float4*)Ks[jl];
            const float4* qr = (const float4*)qs[w];
            float acc = 0.0f;
            #pragma unroll
            for (int dq = 0; dq < HD / 4; ++dq) {
                float4 kq = kr[dq]; float4 qq = qr[dq];
                acc += kq.x * qq.x + kq.y * qq.y + kq.z * qq.z + kq.w * qq.w;
            }
            const float bvv = biasg[(((size_t)(b * HEADS + h)) * NTOK + i) * NTOK + j];
            const int mv = adj[i * NTOK + j];
            S[jt * 2 + jr] = acc * scale + (mv > 0 ? bvv : NEG_INF);
        }
    }

    // ---- phase 2: softmax over the row (registers + shuffle butterfly) ----
    float mx = S[0];
    #pragma unroll
    for (int k = 1; k < 8; ++k) mx = fmaxf(mx, S[k]);
    for (int off = 32; off; off >>= 1) mx = fmaxf(mx, __shfl_xor(mx, off, 64));
    float l = 0.0f, p[8];
    #pragma unroll
    for (int k = 0; k < 8; ++k) { p[k] = __expf(S[k] - mx); l += p[k]; }
    for (int off = 32; off; off >>= 1) l += __shfl_xor(l, off, 64);
    const float inv = 1.0f / l;
    #pragma unroll
    for (int k = 0; k < 8; ++k) p[k] *= inv;   // normalized probs, in registers

    // ---- phase 3: O = P @ V  (lane = d; p broadcast via v_readlane) ----
    float acc = 0.0f;
    for (int jt = 0; jt < 4; ++jt) {
        __syncthreads();
        for (int idx = t; idx < 128 * HD; idx += 256) {
            int r = idx >> 6, d = idx & 63;
            Ks[r][d] = V[(b * NTOK + jt * 128 + r) * HID + h * HD + d];
        }
        __syncthreads();
        #pragma unroll
        for (int jr = 0; jr < 2; ++jr) {
            const float pk = p[jt * 2 + jr];
            #pragma unroll
            for (int jj = 0; jj < 64; ++jj) {
                const float pv = lane_bcast(pk, jj);
                acc += pv * Ks[jr * 64 + jj][lane];
            }
        }
    }
    O[(b * NTOK + i) * HID + h * HD + lane] = acc;
}

// ---------------------------------------------------------------------------
// Stage D: out = O @ Wo + bo
// ---------------------------------------------------------------------------
__global__ __launch_bounds__(256) void pga_outproj(
    const float* __restrict__ O, const float* __restrict__ Wo,
    const float* __restrict__ bo, float* __restrict__ out)
{
    __shared__ float xs[16][HID];
    const int m0 = blockIdx.x * 16;
    const int t = threadIdx.x;

    #pragma unroll
    for (int r = 0; r < 16; ++r) xs[r][t] = O[(m0 + r) * HID + t];
    __syncthreads();

    float acc[16];
    const float bcol = bo[t];
    #pragma unroll
    for (int r = 0; r < 16; ++r) acc[r] = bcol;

    for (int kq = 0; kq < HID / 4; ++kq) {
        const float w0 = Wo[(kq * 4 + 0) * HID + t];
        const float w1 = Wo[(kq * 4 + 1) * HID + t];
        const float w2 = Wo[(kq * 4 + 2) * HID + t];
        const float w3 = Wo[(kq * 4 + 3) * HID + t];
        #pragma unroll
        for (int r = 0; r < 16; ++r) {
            float4 xv = ((const float4*)xs[r])[kq];
            acc[r] += xv.x * w0 + xv.y * w1 + xv.z * w2 + xv.w * w3;
        }
    }
    #pragma unroll
    for (int r = 0; r < 16; ++r) out[(m0 + r) * HID + t] = acc[r];
}

extern "C" void kernel_launch(void* const* d_in, const int* in_sizes, int n_in,
                              void* d_out, int out_size, void* d_ws, size_t ws_size,
                              hipStream_t stream) {
    const float* x   = (const float*)d_in[0];
    const int*   adj = (const int*)d_in[1];
    const float* Wq  = (const float*)d_in[2];
    const float* bq  = (const float*)d_in[3];
    const float* Wk  = (const float*)d_in[4];
    const float* bk  = (const float*)d_in[5];
    const float* Wv  = (const float*)d_in[6];
    const float* bv  = (const float*)d_in[7];
    const float* Wo  = (const float*)d_in[8];
    const float* bo  = (const float*)d_in[9];
    const float* Wp1 = (const float*)d_in[10];
    const float* bp1 = (const float*)d_in[11];
    const float* Wp2 = (const float*)d_in[12];
    const float* bp2 = (const float*)d_in[13];
    float* out = (float*)d_out;

    // ws layout (floats): Q,K,V,A,BbT,O each 262144; bias 4194304
    float* ws   = (float*)d_ws;
    float* Q    = ws;
    float* K    = ws + 262144;
    float* V    = ws + 2 * 262144;
    float* A    = ws + 3 * 262144;
    float* BbT  = ws + 4 * 262144;
    float* O    = ws + 5 * 262144;
    float* bias = ws + 6 * 262144;

    pga_proj5<<<dim3(64, 5), 256, 0, stream>>>(x, Wq, bq, Wk, bk, Wv, bv,
                                               Wp1, bp1, Q, K, V, A, BbT);
    pga_bias<<<512, 512, 0, stream>>>(A, BbT, Wp2, bp2, bias);
    pga_attn<<<1024, 256, 0, stream>>>(Q, K, V, bias, adj, O);
    pga_outproj<<<64, 256, 0, stream>>>(O, Wo, bo, out);
}